// Round 1
// baseline (1984.031 us; speedup 1.0000x reference)
//
#include <hip/hip_runtime.h>

#define D_MODEL   256
#define D_HEAD    64
#define N_HEADS   8
#define N_LEVELS  2
#define N_POINTS  4
#define LQ        22000
#define LEN_IN    22000
#define NB        2

// ---------------------------------------------------------------------------
// Kernel A: value = input_flatten @ Wv + bv   (rows = NB*LEN_IN, cols = 512)
// One block per row; 256 threads; each thread computes 2 output columns.
// ---------------------------------------------------------------------------
__global__ __launch_bounds__(256) void value_gemm_kernel(
    const float* __restrict__ in,    // (NB*LEN_IN, 256)
    const float* __restrict__ Wv,    // (256, 512) row-major
    const float* __restrict__ bv,    // (512)
    float* __restrict__ value)       // (NB*LEN_IN, 512)
{
    const int row = blockIdx.x;
    const int t   = threadIdx.x;

    __shared__ float s_in[D_MODEL];
    s_in[t] = in[(size_t)row * D_MODEL + t];
    __syncthreads();

    float acc0 = bv[t];
    float acc1 = bv[t + 256];
    #pragma unroll 8
    for (int k = 0; k < D_MODEL; ++k) {
        const float x = s_in[k];
        acc0 = fmaf(x, Wv[k * 512 + t],        acc0);
        acc1 = fmaf(x, Wv[k * 512 + t + 256],  acc1);
    }
    value[(size_t)row * 512 + t]       = acc0;
    value[(size_t)row * 512 + t + 256] = acc1;
}

// ---------------------------------------------------------------------------
// Kernel B: fused offsets/attn GEMV + softmax + bilinear sampling + out GEMV.
// One block (256 threads) per query.
// ---------------------------------------------------------------------------
__global__ __launch_bounds__(256) void msda_fused_kernel(
    const float* __restrict__ query,  // (NB*LQ, 256)
    const float* __restrict__ refp,   // (NB, LQ, 2, 2)
    const float* __restrict__ value,  // (NB, LEN_IN, 8, 64)
    const float* __restrict__ Woff,   // (256, 128)
    const float* __restrict__ boff,   // (128)
    const float* __restrict__ Wattn,  // (256, 64)
    const float* __restrict__ battn,  // (64)
    const float* __restrict__ Wo,     // (512, 256)
    const float* __restrict__ bo,     // (256)
    float* __restrict__ out)          // (NB*LQ, 256)
{
    const int qi = blockIdx.x;           // 0 .. NB*LQ-1
    const int n  = qi / LQ;
    const int t  = threadIdx.x;

    __shared__ float s_q[D_MODEL];
    __shared__ float s_off[N_HEADS * N_LEVELS * N_POINTS * 2];  // 128
    __shared__ float s_aw[N_HEADS * N_LEVELS * N_POINTS];       // 64
    __shared__ float s_samp[N_HEADS * D_HEAD];                  // 512

    s_q[t] = query[(size_t)qi * D_MODEL + t];
    __syncthreads();

    // ---- offsets and attention logits (GEMV) ----
    if (t < 128) {
        float acc = boff[t];
        #pragma unroll 8
        for (int k = 0; k < D_MODEL; ++k)
            acc = fmaf(s_q[k], Woff[k * 128 + t], acc);
        s_off[t] = acc;
    } else if (t < 192) {
        const int c = t - 128;
        float acc = battn[c];
        #pragma unroll 8
        for (int k = 0; k < D_MODEL; ++k)
            acc = fmaf(s_q[k], Wattn[k * 64 + c], acc);
        s_aw[c] = acc;
    }
    __syncthreads();

    // ---- softmax over the 8 (level,point) logits of each head ----
    if (t < N_HEADS) {
        float m = -1e30f;
        #pragma unroll
        for (int j = 0; j < 8; ++j) m = fmaxf(m, s_aw[t * 8 + j]);
        float e[8];
        float s = 0.f;
        #pragma unroll
        for (int j = 0; j < 8; ++j) { e[j] = __expf(s_aw[t * 8 + j] - m); s += e[j]; }
        const float inv = 1.f / s;
        #pragma unroll
        for (int j = 0; j < 8; ++j) s_aw[t * 8 + j] = e[j] * inv;
    }
    __syncthreads();

    // ---- bilinear sampling: thread t handles head h = t>>5, dims {2*dp, 2*dp+1} ----
    const int h  = t >> 5;
    const int dp = t & 31;

    float acc0 = 0.f, acc1 = 0.f;

    const int lvlH[N_LEVELS]     = {100, 176 / 2 == 0 ? 0 : 100, };  // placeholder avoided below
    (void)lvlH;

    #pragma unroll
    for (int l = 0; l < N_LEVELS; ++l) {
        const int Hl = (l == 0) ? 100 : 50;
        const int Wl = (l == 0) ? 176 : 88;
        const int start = (l == 0) ? 0 : 17600;

        const float rx = refp[((size_t)qi * N_LEVELS + l) * 2 + 0];
        const float ry = refp[((size_t)qi * N_LEVELS + l) * 2 + 1];

        #pragma unroll
        for (int p = 0; p < N_POINTS; ++p) {
            const int oidx = ((h * N_LEVELS + l) * N_POINTS + p) * 2;
            const float ox = s_off[oidx + 0];
            const float oy = s_off[oidx + 1];
            const float aw = s_aw[h * (N_LEVELS * N_POINTS) + l * N_POINTS + p];

            // x = ((rx+ox)/Wl)*Wl - 0.5 == rx+ox-0.5 (normalizer cancels)
            const float x = rx + ox - 0.5f;
            const float y = ry + oy - 0.5f;
            const float x0f = floorf(x), y0f = floorf(y);
            const float fx = x - x0f,   fy = y - y0f;
            const int x0 = (int)x0f,    y0 = (int)y0f;

            const float w00 = (1.f - fx) * (1.f - fy);
            const float w10 = fx * (1.f - fy);
            const float w01 = (1.f - fx) * fy;
            const float w11 = fx * fy;

            #pragma unroll
            for (int corner = 0; corner < 4; ++corner) {
                const int dx = corner & 1;
                const int dy = corner >> 1;
                const int xi = x0 + dx;
                const int yi = y0 + dy;
                const bool valid = (xi >= 0) & (xi < Wl) & (yi >= 0) & (yi < Hl);
                float w = (corner == 0) ? w00 : (corner == 1) ? w10 : (corner == 2) ? w01 : w11;
                w = valid ? (w * aw) : 0.f;

                const int xc = min(max(xi, 0), Wl - 1);
                const int yc = min(max(yi, 0), Hl - 1);
                const int idx = start + yc * Wl + xc;

                const float2 v = *reinterpret_cast<const float2*>(
                    value + ((((size_t)n * LEN_IN + idx) * N_HEADS + h) * D_HEAD + 2 * dp));
                acc0 = fmaf(w, v.x, acc0);
                acc1 = fmaf(w, v.y, acc1);
            }
        }
    }

    s_samp[h * D_HEAD + 2 * dp]     = acc0;
    s_samp[h * D_HEAD + 2 * dp + 1] = acc1;
    __syncthreads();

    // ---- output projection: out[qi, t] = sum_k s_samp[k] * Wo[k, t] + bo[t] ----
    float o = bo[t];
    #pragma unroll 8
    for (int k = 0; k < 512; ++k)
        o = fmaf(s_samp[k], Wo[k * 256 + t], o);
    out[(size_t)qi * 256 + t] = o;
}

// ---------------------------------------------------------------------------
extern "C" void kernel_launch(void* const* d_in, const int* in_sizes, int n_in,
                              void* d_out, int out_size, void* d_ws, size_t ws_size,
                              hipStream_t stream)
{
    const float* query  = (const float*)d_in[0];
    const float* refp   = (const float*)d_in[1];
    const float* inflat = (const float*)d_in[2];
    const float* Wv     = (const float*)d_in[3];
    const float* bv     = (const float*)d_in[4];
    const float* Woff   = (const float*)d_in[5];
    const float* boff   = (const float*)d_in[6];
    const float* Wattn  = (const float*)d_in[7];
    const float* battn  = (const float*)d_in[8];
    const float* Wo     = (const float*)d_in[9];
    const float* bo     = (const float*)d_in[10];

    float* value = (float*)d_ws;   // (NB, LEN_IN, 8, 64) = 90.1 MB

    value_gemm_kernel<<<NB * LEN_IN, 256, 0, stream>>>(inflat, Wv, bv, value);
    msda_fused_kernel<<<NB * LQ, 256, 0, stream>>>(query, refp, value,
                                                   Woff, boff, Wattn, battn,
                                                   Wo, bo, (float*)d_out);
}

// Round 2
// 487.329 us; speedup vs baseline: 4.0712x; 4.0712x over previous
//
#include <hip/hip_runtime.h>

#define LQ        22000
#define LEN_IN    22000
#define NB        2

typedef _Float16 half8 __attribute__((ext_vector_type(8)));
typedef _Float16 half4 __attribute__((ext_vector_type(4)));
typedef float    floatx4 __attribute__((ext_vector_type(4)));

// ---------------------------------------------------------------------------
// Weight prep: fp32 (K x N) -> f16 transposed (N x K)
// ---------------------------------------------------------------------------
__global__ void transpose_f16_kernel(const float* __restrict__ src,
                                     _Float16* __restrict__ dst, int K, int N)
{
    int i = blockIdx.x * blockDim.x + threadIdx.x;
    if (i < K * N) {
        int k = i / N, n = i % N;
        dst[(size_t)n * K + k] = (_Float16)src[i];
    }
}

__global__ void biascat_kernel(const float* __restrict__ boff,
                               const float* __restrict__ battn,
                               float* __restrict__ biascat)
{
    int i = threadIdx.x;
    if (i < 128) biascat[i] = boff[i];
    else if (i < 192) biascat[i] = battn[i - 128];
}

// fp32 -> f16 elementwise (n4 = count/4)
__global__ void f32_to_f16_kernel(const float* __restrict__ src,
                                  _Float16* __restrict__ dst, int n4)
{
    int i = blockIdx.x * blockDim.x + threadIdx.x;
    const int stride = gridDim.x * blockDim.x;
    for (; i < n4; i += stride) {
        float4 v = reinterpret_cast<const float4*>(src)[i];
        half4 h;
        h[0] = (_Float16)v.x; h[1] = (_Float16)v.y;
        h[2] = (_Float16)v.z; h[3] = (_Float16)v.w;
        reinterpret_cast<half4*>(dst)[i] = h;
    }
}

// ---------------------------------------------------------------------------
// Generic f16 MFMA GEMM: C(MxN) = A(MxK) @ B(KxN) + bias, B given as BT(NxK).
// 64x64 tile, BK=64, 256 threads = 4 waves, wave -> 32x32 (2x2 frags 16x16x32).
// ---------------------------------------------------------------------------
template<bool OUT_F16>
__global__ __launch_bounds__(256) void gemm_f16_kernel(
    const _Float16* __restrict__ A,
    const _Float16* __restrict__ BT,
    const float* __restrict__ bias,
    void* __restrict__ C,
    int M, int N, int K)
{
    __shared__ __align__(16) _Float16 sA[64][72];
    __shared__ __align__(16) _Float16 sBT[64][72];

    const int t  = threadIdx.x;
    const int m0 = blockIdx.x * 64;
    const int n0 = blockIdx.y * 64;

    const int w    = t >> 6;
    const int lane = t & 63;
    const int wm   = (w >> 1) * 32;     // wave row offset in tile
    const int wn   = (w & 1) * 32;      // wave col offset in tile
    const int lrow = lane & 15;
    const int lk   = (lane >> 4) * 8;

    const int r   = t >> 2;             // staging row 0..63
    const int seg = t & 3;              // staging k-segment (16 f16 each)

    floatx4 acc[2][2] = {};

    for (int k0 = 0; k0 < K; k0 += 64) {
        // ---- stage A tile (row-guarded) ----
        {
            int4 v0 = {0,0,0,0}, v1 = {0,0,0,0};
            const int arow = m0 + r;
            if (arow < M) {
                const _Float16* src = A + (size_t)arow * K + k0 + seg * 16;
                v0 = *reinterpret_cast<const int4*>(src);
                v1 = *reinterpret_cast<const int4*>(src + 8);
            }
            *reinterpret_cast<int4*>(&sA[r][seg * 16])     = v0;
            *reinterpret_cast<int4*>(&sA[r][seg * 16 + 8]) = v1;
        }
        // ---- stage BT tile ----
        {
            const _Float16* src = BT + (size_t)(n0 + r) * K + k0 + seg * 16;
            *reinterpret_cast<int4*>(&sBT[r][seg * 16])     = *reinterpret_cast<const int4*>(src);
            *reinterpret_cast<int4*>(&sBT[r][seg * 16 + 8]) = *reinterpret_cast<const int4*>(src + 8);
        }
        __syncthreads();

        #pragma unroll
        for (int kb = 0; kb < 2; ++kb) {
            const int ko = kb * 32 + lk;
            half8 a0 = *reinterpret_cast<const half8*>(&sA[wm + lrow][ko]);
            half8 a1 = *reinterpret_cast<const half8*>(&sA[wm + 16 + lrow][ko]);
            half8 b0 = *reinterpret_cast<const half8*>(&sBT[wn + lrow][ko]);
            half8 b1 = *reinterpret_cast<const half8*>(&sBT[wn + 16 + lrow][ko]);
            acc[0][0] = __builtin_amdgcn_mfma_f32_16x16x32_f16(a0, b0, acc[0][0], 0, 0, 0);
            acc[0][1] = __builtin_amdgcn_mfma_f32_16x16x32_f16(a0, b1, acc[0][1], 0, 0, 0);
            acc[1][0] = __builtin_amdgcn_mfma_f32_16x16x32_f16(a1, b0, acc[1][0], 0, 0, 0);
            acc[1][1] = __builtin_amdgcn_mfma_f32_16x16x32_f16(a1, b1, acc[1][1], 0, 0, 0);
        }
        __syncthreads();
    }

    // ---- store: C frag mapping col=lane&15, row=(lane>>4)*4+reg ----
    const int crow = (lane >> 4) * 4;
    const int ccol = lane & 15;
    #pragma unroll
    for (int fm = 0; fm < 2; ++fm) {
        #pragma unroll
        for (int fn = 0; fn < 2; ++fn) {
            const int col = n0 + wn + fn * 16 + ccol;
            const float b = bias[col];
            #pragma unroll
            for (int r2 = 0; r2 < 4; ++r2) {
                const int row = m0 + wm + fm * 16 + crow + r2;
                if (row < M) {
                    const float val = acc[fm][fn][r2] + b;
                    if (OUT_F16)
                        ((_Float16*)C)[(size_t)row * N + col] = (_Float16)val;
                    else
                        ((float*)C)[(size_t)row * N + col] = val;
                }
            }
        }
    }
}

// ---------------------------------------------------------------------------
// Sampler: one wave per (query, head); lane = dim. Reads f16 value + logits,
// softmax in-register, 64 bilinear samples, writes f16 sampled row.
// ---------------------------------------------------------------------------
__global__ __launch_bounds__(512) void sampler_kernel(
    const _Float16* __restrict__ value,   // (22000, 8, 64) f16 (this image)
    const _Float16* __restrict__ logits,  // (22000, 192) f16 (this image)
    const float*    __restrict__ refp,    // (22000, 2, 2) (this image)
    _Float16* __restrict__ sampled)       // (22000, 512) f16
{
    const int q = blockIdx.x;
    const int h = threadIdx.x >> 6;
    const int d = threadIdx.x & 63;

    const _Float16* lg = logits + (size_t)q * 192;

    // softmax over the 8 (level,point) logits of head h (redundant per lane)
    float wgt[8];
    float m = -1e30f;
    #pragma unroll
    for (int j = 0; j < 8; ++j) {
        wgt[j] = (float)lg[128 + h * 8 + j];
        m = fmaxf(m, wgt[j]);
    }
    float s = 0.f;
    #pragma unroll
    for (int j = 0; j < 8; ++j) { wgt[j] = __expf(wgt[j] - m); s += wgt[j]; }
    const float inv = 1.f / s;

    float acc = 0.f;
    #pragma unroll
    for (int l = 0; l < 2; ++l) {
        const int Hl = l ? 50 : 100;
        const int Wl = l ? 88 : 176;
        const int st = l ? 17600 : 0;
        const float rx = refp[q * 4 + l * 2 + 0];
        const float ry = refp[q * 4 + l * 2 + 1];
        #pragma unroll
        for (int p = 0; p < 4; ++p) {
            const float ox = (float)lg[h * 16 + l * 8 + p * 2 + 0];
            const float oy = (float)lg[h * 16 + l * 8 + p * 2 + 1];
            const float aw = wgt[l * 4 + p] * inv;

            // ((rx+ox)/Wl)*Wl - 0.5 == rx+ox-0.5 (normalizer cancels)
            const float x = rx + ox - 0.5f;
            const float y = ry + oy - 0.5f;
            const float x0f = floorf(x), y0f = floorf(y);
            const float fx = x - x0f, fy = y - y0f;
            const int x0 = (int)x0f, y0 = (int)y0f;

            #pragma unroll
            for (int c = 0; c < 4; ++c) {
                const int xi = x0 + (c & 1);
                const int yi = y0 + (c >> 1);
                const bool valid = (xi >= 0) & (xi < Wl) & (yi >= 0) & (yi < Hl);
                const float wb = ((c & 1) ? fx : 1.f - fx) * ((c >> 1) ? fy : 1.f - fy);
                const float wz = valid ? wb * aw : 0.f;
                const int xc = min(max(xi, 0), Wl - 1);
                const int yc = min(max(yi, 0), Hl - 1);
                const int idx = st + yc * Wl + xc;
                acc = fmaf(wz, (float)value[((size_t)idx * 8 + h) * 64 + d], acc);
            }
        }
    }
    sampled[(size_t)q * 512 + h * 64 + d] = (_Float16)acc;
}

// ---------------------------------------------------------------------------
extern "C" void kernel_launch(void* const* d_in, const int* in_sizes, int n_in,
                              void* d_out, int out_size, void* d_ws, size_t ws_size,
                              hipStream_t stream)
{
    const float* query  = (const float*)d_in[0];
    const float* refp   = (const float*)d_in[1];
    const float* inflat = (const float*)d_in[2];
    const float* Wv     = (const float*)d_in[3];
    const float* bv     = (const float*)d_in[4];
    const float* Woff   = (const float*)d_in[5];
    const float* boff   = (const float*)d_in[6];
    const float* Wattn  = (const float*)d_in[7];
    const float* battn  = (const float*)d_in[8];
    const float* Wo     = (const float*)d_in[9];
    const float* bo     = (const float*)d_in[10];
    float* out = (float*)d_out;

    // ---- workspace layout (bytes), all 256-aligned ----
    char* ws = (char*)d_ws;
    size_t off = 0;
    auto take = [&](size_t bytes) { char* p = ws + off; off = (off + bytes + 255) & ~(size_t)255; return p; };
    _Float16* WvT     = (_Float16*)take(512 * 256 * 2);
    _Float16* WofT    = (_Float16*)take(192 * 256 * 2);
    _Float16* WoT     = (_Float16*)take(256 * 512 * 2);
    float*    biascat = (float*)   take(192 * 4);
    _Float16* inbf    = (_Float16*)take((size_t)LEN_IN * 256 * 2);
    _Float16* qbf     = (_Float16*)take((size_t)LQ * 256 * 2);
    _Float16* value   = (_Float16*)take((size_t)LEN_IN * 512 * 2);
    _Float16* logits  = (_Float16*)take((size_t)LQ * 192 * 2);
    _Float16* sampled = (_Float16*)take((size_t)LQ * 512 * 2);

    // ---- weight prep (once per launch) ----
    transpose_f16_kernel<<<(256 * 512 + 255) / 256, 256, 0, stream>>>(Wv, WvT, 256, 512);
    transpose_f16_kernel<<<(256 * 128 + 255) / 256, 256, 0, stream>>>(Woff, WofT, 256, 128);
    transpose_f16_kernel<<<(256 * 64 + 255) / 256, 256, 0, stream>>>(Wattn, WofT + 128 * 256, 256, 64);
    transpose_f16_kernel<<<(512 * 256 + 255) / 256, 256, 0, stream>>>(Wo, WoT, 512, 256);
    biascat_kernel<<<1, 256, 0, stream>>>(boff, battn, biascat);

    const int MGRID = (LQ + 63) / 64;   // 344

    for (int n = 0; n < NB; ++n) {
        const float* in_n  = inflat + (size_t)n * LEN_IN * 256;
        const float* q_n   = query  + (size_t)n * LQ * 256;
        const float* rp_n  = refp   + (size_t)n * LQ * 4;
        float*       out_n = out    + (size_t)n * LQ * 256;

        f32_to_f16_kernel<<<2048, 256, 0, stream>>>(in_n, inbf, LEN_IN * 256 / 4);
        f32_to_f16_kernel<<<2048, 256, 0, stream>>>(q_n, qbf, LQ * 256 / 4);

        gemm_f16_kernel<true><<<dim3(MGRID, 8), 256, 0, stream>>>(
            inbf, WvT, bv, value, LEN_IN, 512, 256);
        gemm_f16_kernel<true><<<dim3(MGRID, 3), 256, 0, stream>>>(
            qbf, WofT, biascat, logits, LQ, 192, 256);

        sampler_kernel<<<LQ, 512, 0, stream>>>(value, logits, rp_n, sampled);

        gemm_f16_kernel<false><<<dim3(MGRID, 4), 256, 0, stream>>>(
            sampled, WoT, bo, out_n, LQ, 256, 512);
    }
}

// Round 3
// 384.312 us; speedup vs baseline: 5.1626x; 1.2681x over previous
//
#include <hip/hip_runtime.h>

#define LQ        22000
#define LEN_IN    22000
#define NB        2

typedef _Float16 half8 __attribute__((ext_vector_type(8)));
typedef _Float16 half4 __attribute__((ext_vector_type(4)));
typedef float    floatx4 __attribute__((ext_vector_type(4)));

// ---------------------------------------------------------------------------
// One-shot prep: all weight transposes (fp32 -> f16, (K,N)->(N,K)) + bias cat.
// ---------------------------------------------------------------------------
__global__ __launch_bounds__(256) void prep_kernel(
    const float* __restrict__ Wv, const float* __restrict__ Woff,
    const float* __restrict__ Wattn, const float* __restrict__ Wo,
    const float* __restrict__ boff, const float* __restrict__ battn,
    _Float16* __restrict__ WvT, _Float16* __restrict__ WofT,
    _Float16* __restrict__ WoT, float* __restrict__ biascat)
{
    const int i = blockIdx.x * 256 + threadIdx.x;
    if (i < 131072) {                       // Wv (256,512) -> WvT (512,256)
        int k = i >> 9, n = i & 511;
        WvT[n * 256 + k] = (_Float16)Wv[i];
    } else if (i < 163840) {                // Woff (256,128) -> WofT rows 0..127
        int j = i - 131072; int k = j >> 7, n = j & 127;
        WofT[n * 256 + k] = (_Float16)Woff[j];
    } else if (i < 180224) {                // Wattn (256,64) -> WofT rows 128..191
        int j = i - 163840; int k = j >> 6, n = j & 63;
        WofT[(128 + n) * 256 + k] = (_Float16)Wattn[j];
    } else if (i < 311296) {                // Wo (512,256) -> WoT (256,512)
        int j = i - 180224; int k = j >> 8, n = j & 255;
        WoT[n * 512 + k] = (_Float16)Wo[j];
    } else if (i < 311488) {                // bias concat (192)
        int j = i - 311296;
        biascat[j] = (j < 128) ? boff[j] : battn[j - 128];
    }
}

// fp32 -> f16 elementwise (n4 = count/4)
__global__ void f32_to_f16_kernel(const float* __restrict__ src,
                                  _Float16* __restrict__ dst, int n4)
{
    int i = blockIdx.x * blockDim.x + threadIdx.x;
    const int stride = gridDim.x * blockDim.x;
    for (; i < n4; i += stride) {
        float4 v = reinterpret_cast<const float4*>(src)[i];
        half4 h;
        h[0] = (_Float16)v.x; h[1] = (_Float16)v.y;
        h[2] = (_Float16)v.z; h[3] = (_Float16)v.w;
        reinterpret_cast<half4*>(dst)[i] = h;
    }
}

// ---------------------------------------------------------------------------
// f16 MFMA GEMM: C(MxN) = A(MxK) @ B(KxN) + bias, B given as BT(NxK).
// 128x64 tile, BK=64, 256 threads = 4 waves; wave w -> rows w*32..w*32+31,
// all 64 cols (2x4 frags of 16x16x32).
// ---------------------------------------------------------------------------
template<bool OUT_F16>
__global__ __launch_bounds__(256) void gemm_f16_kernel(
    const _Float16* __restrict__ A,
    const _Float16* __restrict__ BT,
    const float* __restrict__ bias,
    void* __restrict__ C,
    int M, int N, int K)
{
    __shared__ __align__(16) _Float16 sA[128][72];
    __shared__ __align__(16) _Float16 sB[64][72];

    const int t  = threadIdx.x;
    const int m0 = blockIdx.x * 128;
    const int n0 = blockIdx.y * 64;

    const int w    = t >> 6;
    const int lane = t & 63;
    const int wm   = w * 32;
    const int lrow = lane & 15;
    const int lk   = (lane >> 4) * 8;

    const int ar = t >> 1;            // A staging row 0..127
    const int ah = (t & 1) * 32;      // A staging k-offset (32 f16)
    const int br = t >> 2;            // B staging row 0..63
    const int bs = (t & 3) * 16;      // B staging k-offset (16 f16)

    floatx4 acc[2][4] = {};

    for (int k0 = 0; k0 < K; k0 += 64) {
        {   // stage A (row-guarded)
            int4 v0 = {0,0,0,0}, v1 = {0,0,0,0}, v2 = {0,0,0,0}, v3 = {0,0,0,0};
            const int arow = m0 + ar;
            if (arow < M) {
                const int4* src = reinterpret_cast<const int4*>(A + (size_t)arow * K + k0 + ah);
                v0 = src[0]; v1 = src[1]; v2 = src[2]; v3 = src[3];
            }
            int4* dst = reinterpret_cast<int4*>(&sA[ar][ah]);
            dst[0] = v0; dst[1] = v1; dst[2] = v2; dst[3] = v3;
        }
        {   // stage B
            const int4* src = reinterpret_cast<const int4*>(BT + (size_t)(n0 + br) * K + k0 + bs);
            int4* dst = reinterpret_cast<int4*>(&sB[br][bs]);
            dst[0] = src[0]; dst[1] = src[1];
        }
        __syncthreads();

        #pragma unroll
        for (int kb = 0; kb < 2; ++kb) {
            const int ko = kb * 32 + lk;
            half8 a0 = *reinterpret_cast<const half8*>(&sA[wm + lrow][ko]);
            half8 a1 = *reinterpret_cast<const half8*>(&sA[wm + 16 + lrow][ko]);
            half8 b0 = *reinterpret_cast<const half8*>(&sB[lrow][ko]);
            half8 b1 = *reinterpret_cast<const half8*>(&sB[16 + lrow][ko]);
            half8 b2 = *reinterpret_cast<const half8*>(&sB[32 + lrow][ko]);
            half8 b3 = *reinterpret_cast<const half8*>(&sB[48 + lrow][ko]);
            acc[0][0] = __builtin_amdgcn_mfma_f32_16x16x32_f16(a0, b0, acc[0][0], 0, 0, 0);
            acc[0][1] = __builtin_amdgcn_mfma_f32_16x16x32_f16(a0, b1, acc[0][1], 0, 0, 0);
            acc[0][2] = __builtin_amdgcn_mfma_f32_16x16x32_f16(a0, b2, acc[0][2], 0, 0, 0);
            acc[0][3] = __builtin_amdgcn_mfma_f32_16x16x32_f16(a0, b3, acc[0][3], 0, 0, 0);
            acc[1][0] = __builtin_amdgcn_mfma_f32_16x16x32_f16(a1, b0, acc[1][0], 0, 0, 0);
            acc[1][1] = __builtin_amdgcn_mfma_f32_16x16x32_f16(a1, b1, acc[1][1], 0, 0, 0);
            acc[1][2] = __builtin_amdgcn_mfma_f32_16x16x32_f16(a1, b2, acc[1][2], 0, 0, 0);
            acc[1][3] = __builtin_amdgcn_mfma_f32_16x16x32_f16(a1, b3, acc[1][3], 0, 0, 0);
        }
        __syncthreads();
    }

    // store: C frag mapping col=lane&15, row=(lane>>4)*4+reg
    const int crow = (lane >> 4) * 4;
    const int ccol = lane & 15;
    #pragma unroll
    for (int fm = 0; fm < 2; ++fm) {
        #pragma unroll
        for (int fn = 0; fn < 4; ++fn) {
            const int col = n0 + fn * 16 + ccol;
            const float b = bias[col];
            #pragma unroll
            for (int r2 = 0; r2 < 4; ++r2) {
                const int row = m0 + wm + fm * 16 + crow + r2;
                if (row < M) {
                    const float val = acc[fm][fn][r2] + b;
                    if (OUT_F16)
                        ((_Float16*)C)[(size_t)row * N + col] = (_Float16)val;
                    else
                        ((float*)C)[(size_t)row * N + col] = val;
                }
            }
        }
    }
}

// ---------------------------------------------------------------------------
// Sampler: block = 256 threads = 2 queries (128 threads each).
// Phase 1: one wave per query (lane = sample id 0..63) computes softmax +
//          bilinear metadata -> LDS (4 idx + 4 weights per sample).
// Phase 2: 128 threads per query, thread = (head, 4 dims); pure gather+FMA.
// ---------------------------------------------------------------------------
__global__ __launch_bounds__(256) void sampler_kernel(
    const _Float16* __restrict__ value,   // (22000, 8, 64) f16
    const _Float16* __restrict__ logits,  // (22000, 192) f16
    const float*    __restrict__ refp,    // (22000, 2, 2)
    _Float16* __restrict__ sampled)       // (22000, 512) f16
{
    const int t  = threadIdx.x;
    const int qh = t >> 7;                 // 0/1: which query of the block
    const int q  = blockIdx.x * 2 + qh;
    const int tl = t & 127;

    // padded stride 9 -> 4-bank step between heads (avoids 4-way conflict)
    __shared__ __align__(16) int4   s_idx[2][72];
    __shared__ __align__(16) float4 s_w[2][72];

    if (tl < 64) {
        const int s = tl;                  // sample id
        const int h = s >> 3;
        const int l = (s >> 2) & 1;
        const int p = s & 3;
        const _Float16* lg = logits + (size_t)q * 192;

        // softmax weight of (l,p) within head h
        float logit[8];
        float m = -1e30f;
        #pragma unroll
        for (int j = 0; j < 8; ++j) {
            logit[j] = (float)lg[128 + h * 8 + j];
            m = fmaxf(m, logit[j]);
        }
        float den = 0.f;
        #pragma unroll
        for (int j = 0; j < 8; ++j) den += __expf(logit[j] - m);
        const float aw = __expf(logit[l * 4 + p] - m) / den;

        const int Hl = l ? 50 : 100;
        const int Wl = l ? 88 : 176;
        const int st = l ? 17600 : 0;
        const float rx = refp[q * 4 + l * 2 + 0];
        const float ry = refp[q * 4 + l * 2 + 1];
        const float ox = (float)lg[h * 16 + l * 8 + p * 2 + 0];
        const float oy = (float)lg[h * 16 + l * 8 + p * 2 + 1];

        // ((r+o)/W)*W - 0.5 == r+o-0.5 (normalizer cancels)
        const float x = rx + ox - 0.5f;
        const float y = ry + oy - 0.5f;
        const float x0f = floorf(x), y0f = floorf(y);
        const float fx = x - x0f, fy = y - y0f;
        const int x0 = (int)x0f, y0 = (int)y0f;

        int4  iv;
        float4 wv;
        #pragma unroll
        for (int c = 0; c < 4; ++c) {
            const int xi = x0 + (c & 1);
            const int yi = y0 + (c >> 1);
            const bool valid = (xi >= 0) & (xi < Wl) & (yi >= 0) & (yi < Hl);
            const float wb = ((c & 1) ? fx : 1.f - fx) * ((c >> 1) ? fy : 1.f - fy);
            const int xc = min(max(xi, 0), Wl - 1);
            const int yc = min(max(yi, 0), Hl - 1);
            iv[c] = st + yc * Wl + xc;
            wv[c] = valid ? wb * aw : 0.f;
        }
        const int slot = h * 9 + (l * 4 + p);
        s_idx[qh][slot] = iv;
        s_w[qh][slot]   = wv;
    }
    __syncthreads();

    const int h  = tl >> 4;
    const int d4 = (tl & 15) * 4;
    const _Float16* vbase = value + h * 64 + d4;

    float a0 = 0.f, a1 = 0.f, a2 = 0.f, a3 = 0.f;
    #pragma unroll
    for (int s8 = 0; s8 < 8; ++s8) {
        const int4   iv = s_idx[qh][h * 9 + s8];
        const float4 wv = s_w[qh][h * 9 + s8];
        #pragma unroll
        for (int c = 0; c < 4; ++c) {
            const half4 v = *reinterpret_cast<const half4*>(vbase + (size_t)iv[c] * 512);
            const float w = wv[c];
            a0 = fmaf(w, (float)v[0], a0);
            a1 = fmaf(w, (float)v[1], a1);
            a2 = fmaf(w, (float)v[2], a2);
            a3 = fmaf(w, (float)v[3], a3);
        }
    }
    half4 o;
    o[0] = (_Float16)a0; o[1] = (_Float16)a1;
    o[2] = (_Float16)a2; o[3] = (_Float16)a3;
    *reinterpret_cast<half4*>(sampled + (size_t)q * 512 + h * 64 + d4) = o;
}

// ---------------------------------------------------------------------------
extern "C" void kernel_launch(void* const* d_in, const int* in_sizes, int n_in,
                              void* d_out, int out_size, void* d_ws, size_t ws_size,
                              hipStream_t stream)
{
    const float* query  = (const float*)d_in[0];
    const float* refp   = (const float*)d_in[1];
    const float* inflat = (const float*)d_in[2];
    const float* Wv     = (const float*)d_in[3];
    const float* bv     = (const float*)d_in[4];
    const float* Woff   = (const float*)d_in[5];
    const float* boff   = (const float*)d_in[6];
    const float* Wattn  = (const float*)d_in[7];
    const float* battn  = (const float*)d_in[8];
    const float* Wo     = (const float*)d_in[9];
    const float* bo     = (const float*)d_in[10];
    float* out = (float*)d_out;

    char* ws = (char*)d_ws;
    size_t off = 0;
    auto take = [&](size_t bytes) { char* p = ws + off; off = (off + bytes + 255) & ~(size_t)255; return p; };
    _Float16* WvT     = (_Float16*)take(512 * 256 * 2);
    _Float16* WofT    = (_Float16*)take(192 * 256 * 2);
    _Float16* WoT     = (_Float16*)take(256 * 512 * 2);
    float*    biascat = (float*)   take(192 * 4);
    _Float16* inbf    = (_Float16*)take((size_t)LEN_IN * 256 * 2);
    _Float16* qbf     = (_Float16*)take((size_t)LQ * 256 * 2);
    _Float16* value   = (_Float16*)take((size_t)LEN_IN * 512 * 2);
    _Float16* logits  = (_Float16*)take((size_t)LQ * 192 * 2);
    _Float16* sampled = (_Float16*)take((size_t)LQ * 512 * 2);

    prep_kernel<<<(311488 + 255) / 256, 256, 0, stream>>>(
        Wv, Woff, Wattn, Wo, boff, battn, WvT, WofT, WoT, biascat);

    const int MGRID = (LQ + 127) / 128;   // 172

    for (int n = 0; n < NB; ++n) {
        const float* in_n  = inflat + (size_t)n * LEN_IN * 256;
        const float* q_n   = query  + (size_t)n * LQ * 256;
        const float* rp_n  = refp   + (size_t)n * LQ * 4;
        float*       out_n = out    + (size_t)n * LQ * 256;

        f32_to_f16_kernel<<<1024, 256, 0, stream>>>(in_n, inbf, LEN_IN * 256 / 4);
        f32_to_f16_kernel<<<1024, 256, 0, stream>>>(q_n, qbf, LQ * 256 / 4);

        gemm_f16_kernel<true><<<dim3(MGRID, 8), 256, 0, stream>>>(
            inbf, WvT, bv, value, LEN_IN, 512, 256);
        gemm_f16_kernel<true><<<dim3(MGRID, 3), 256, 0, stream>>>(
            qbf, WofT, biascat, logits, LQ, 192, 256);

        sampler_kernel<<<LQ / 2, 256, 0, stream>>>(value, logits, rp_n, sampled);

        gemm_f16_kernel<false><<<dim3(MGRID, 4), 256, 0, stream>>>(
            sampled, WoT, bo, out_n, LQ, 256, 512);
    }
}